// Round 13
// baseline (100.872 us; speedup 1.0000x reference)
//
#include <hip/hip_runtime.h>
#include <hip/hip_bf16.h>
#include <stdint.h>

// Problem constants (B=64, L=512, H=32, D=128, 21 amino acids)
#define NH  32
#define NL  512
#define ND  128
#define NB  64
#define NAA 21

// ws layout: Qb/Kb bf16 swizzled 8KB tiles [h][pt 0..7][dc 0..1]
#define QB_OFF (16u << 20)
#define KB_OFF (18u << 20)

typedef short bf16x8 __attribute__((ext_vector_type(8)));
typedef float f32x4  __attribute__((ext_vector_type(4)));

static __device__ __forceinline__ uint32_t bf16rtn(float f) {
    uint32_t u = __float_as_uint(f);
    return (u + 0x7fffu + ((u >> 16) & 1u)) >> 16;
}
static __device__ __forceinline__ void gl16(const void* g, void* l) {
    __builtin_amdgcn_global_load_lds(
        (const __attribute__((address_space(1))) uint32_t*)g,
        (__attribute__((address_space(3))) uint32_t*)l, 16, 0, 0);
}
// swizzled byte within a 64x64 bf16 tile: (r*128 + kk*2) ^ ((r&7)<<4)

// ---------------------------------------------------------------------------
// Q,K f32 -> bf16 swizzled tiles.  2^21 threads: bit20 selects Q/K.
__global__ void prep_qk(const float* __restrict__ Q, const float* __restrict__ K,
                        uint32_t* __restrict__ Qb, uint32_t* __restrict__ Kb) {
    uint32_t tid = blockIdx.x * 256 + threadIdx.x;
    const float* src = (tid >> 20) ? K : Q;
    uint32_t*    dst = (tid >> 20) ? Kb : Qb;
    uint32_t p = tid & 0xFFFFFu;
    uint32_t kk2 = p & 31, r = (p >> 5) & 63, dc = (p >> 11) & 1;
    uint32_t pt = (p >> 12) & 7, h = p >> 15;
    uint32_t pos = pt * 64 + r, d0 = dc * 64 + kk2 * 2;
    float2 v = *(const float2*)(src + ((size_t)(h * NL + pos) * ND + d0));
    uint32_t val = bf16rtn(v.x) | (bf16rtn(v.y) << 16);
    uint32_t byte = (r * 128 + kk2 * 4) ^ ((r & 7) << 4);
    dst[((((h * 8 + pt) * 2 + dc)) << 11) + (byte >> 2)] = val;
}

// ---------------------------------------------------------------------------
// FUSED kernel.  Block = (h, it of 64 i-rows), grid 256 = 1 block/CU.
// P1 (scores): S^T = K x Q via MFMA (swapped operands), exp -> bf16 pairs
//     written to LDS A-tile [kc 0..7][64x64 swizzled]; Z in LDS.
// P2 (energy): R[i, n=b*21+c] = sum_k A[i,k]*[x[b,k]==c] for ALL n=1344.
//     A from LDS, one-hot B generated in-register from xs.  No barriers.
// P3: windowed epilogue (8 x 8 rows), dot vs V, /Z, atomicAdd to out.
#define FA_A   0        // 8 x 8192 = 65536  A tiles
#define FA_STG 65536    // Q 16KB @+0, K 32KB @+16384; Racc (8*1349*4=43168) overlays
#define FA_XS  114688   // 64*130*4 = 33280
#define FA_VS  147968   // 441 f32 = 1764 -> pad
#define FA_ZS  149760   // 64 f32
#define FA_TOT 150016

__global__ __launch_bounds__(512, 2)
void fused_energy(const uint8_t* __restrict__ Qb, const uint8_t* __restrict__ Kb,
                  const int* __restrict__ x, const float* __restrict__ V,
                  float* __restrict__ out) {
    extern __shared__ uint8_t smem[];
    uint8_t*  Al  = smem + FA_A;
    uint32_t* xs  = (uint32_t*)(smem + FA_XS);
    float*    Vs  = (float*)(smem + FA_VS);
    float*    Zl  = (float*)(smem + FA_ZS);
    float*    Racc = (float*)(smem + FA_STG);

    int h = blockIdx.x >> 3, it = blockIdx.x & 7;
    int t = threadIdx.x, lane = t & 63, wv = t >> 6;

    // ---- prologue: Q gl16, xs, Vs, Z zero
    const uint8_t* qsrc = Qb + (((size_t)(h * 8 + it) * 2) << 13);
    gl16(qsrc + t * 16,        smem + FA_STG + t * 16);
    gl16(qsrc + 8192 + t * 16, smem + FA_STG + 8192 + t * 16);
    for (int idx = t; idx < 64 * 128; idx += 512) {
        int s = idx >> 7, w = idx & 127;
        int4 xv = *(const int4*)(x + (size_t)s * NL + w * 4);
        xs[s * 130 + w] = (uint32_t)(xv.x & 0xff) | ((uint32_t)(xv.y & 0xff) << 8)
                        | ((uint32_t)(xv.z & 0xff) << 16) | ((uint32_t)(xv.w & 0xff) << 24);
    }
    for (int idx = t; idx < NAA * NAA; idx += 512) Vs[idx] = V[h * (NAA * NAA) + idx];
    if (t < 64) Zl[t] = 0.f;

    // ---- P1: scores (verbatim structure, output to LDS A-tile)
    {
        int wm = wv >> 1, wn = wv & 1;   // 4(Mj) x 2(Ni)
        float zp[2] = {0.f, 0.f};
        for (int sc = 0; sc < 4; ++sc) {
            __syncthreads();   // prev compute done with K stage (1st: Q/xs/Vs/Z)
            const uint8_t* ksrc = Kb + (((size_t)(h * 8 + sc * 2) * 2) << 13);
#pragma unroll
            for (int q = 0; q < 4; ++q)
                gl16(ksrc + q * 8192 + t * 16, smem + FA_STG + 16384 + q * 8192 + t * 16);
            __syncthreads();   // implicit vmcnt(0): K staged

            f32x4 acc[2][2];
#pragma unroll
            for (int fm = 0; fm < 2; ++fm)
#pragma unroll
                for (int fn = 0; fn < 2; ++fn) acc[fm][fn] = (f32x4){0.f,0.f,0.f,0.f};
#pragma unroll
            for (int ks = 0; ks < 4; ++ks) {
                int kb = ((ks & 1) * 32 + (lane >> 4) * 8) * 2;
                int dc = ks >> 1;
                bf16x8 af[2], bfr[2];
#pragma unroll
                for (int fm = 0; fm < 2; ++fm) {
                    int rr = wm * 32 + fm * 16 + (lane & 15);
                    int rt = rr >> 6, r6 = rr & 63;
                    af[fm] = *(bf16x8*)(smem + FA_STG + 16384 + (rt * 2 + dc) * 8192 +
                              (((uint32_t)(r6 * 128 + kb)) ^ ((r6 & 7) << 4)));
                }
#pragma unroll
                for (int fn = 0; fn < 2; ++fn) {
                    int rr = wn * 32 + fn * 16 + (lane & 15);
                    bfr[fn] = *(bf16x8*)(smem + FA_STG + dc * 8192 +
                              (((uint32_t)(rr * 128 + kb)) ^ ((rr & 7) << 4)));
                }
#pragma unroll
                for (int fm = 0; fm < 2; ++fm)
#pragma unroll
                    for (int fn = 0; fn < 2; ++fn)
                        acc[fm][fn] = __builtin_amdgcn_mfma_f32_16x16x32_bf16(
                            af[fm], bfr[fn], acc[fm][fn], 0, 0, 0);
            }
#pragma unroll
            for (int fm = 0; fm < 2; ++fm)
#pragma unroll
                for (int fn = 0; fn < 2; ++fn) {
                    float e0 = __expf(acc[fm][fn][0] * 0.0078125f);
                    float e1 = __expf(acc[fm][fn][1] * 0.0078125f);
                    float e2 = __expf(acc[fm][fn][2] * 0.0078125f);
                    float e3 = __expf(acc[fm][fn][3] * 0.0078125f);
                    zp[fn] += (e0 + e1) + (e2 + e3);
                    uint2 pk;
                    pk.x = bf16rtn(e0) | (bf16rtn(e1) << 16);
                    pk.y = bf16rtn(e2) | (bf16rtn(e3) << 16);
                    int j = sc * 128 + wm * 32 + fm * 16 + (lane >> 4) * 4;  // k index
                    int i = wn * 32 + fn * 16 + (lane & 15);                 // row
                    int kc = j >> 6, kk = j & 63;
                    uint32_t byte = ((uint32_t)(i * 128 + kk * 2)) ^ ((uint32_t)((i & 7) << 4));
                    *(uint2*)(Al + (kc << 13) + byte) = pk;
                }
        }
        zp[0] += __shfl_xor(zp[0], 16); zp[0] += __shfl_xor(zp[0], 32);
        zp[1] += __shfl_xor(zp[1], 16); zp[1] += __shfl_xor(zp[1], 32);
        if (lane < 16) {
            atomicAdd(&Zl[wn * 32 + lane],      zp[0]);
            atomicAdd(&Zl[wn * 32 + 16 + lane], zp[1]);
        }
    }
    __syncthreads();   // A-tile + Z complete; K-stage region free for Racc

    // ---- P2: energy GEMM, no barriers.  8 waves as 2(M)x4(N).
    int wm = wv >> 2, wn = wv & 3;
    int pc[NAA];                       // (b<<8)|c per fn
#pragma unroll
    for (int fn = 0; fn < NAA; ++fn) {
        int n = wn * 336 + fn * 16 + (lane & 15);
        int b = n / 21;
        pc[fn] = (b << 8) | (n - b * 21);
    }

    f32x4 acc[2][NAA];
#pragma unroll
    for (int fm = 0; fm < 2; ++fm)
#pragma unroll
        for (int fn = 0; fn < NAA; ++fn) acc[fm][fn] = (f32x4){0.f,0.f,0.f,0.f};

    for (int q = 0; q < 16; ++q) {     // K-step 32
        int kb = ((q & 1) * 32 + (lane >> 4) * 8) * 2;
        bf16x8 af[2];
#pragma unroll
        for (int fm = 0; fm < 2; ++fm) {
            int r6 = wm * 32 + fm * 16 + (lane & 15);
            af[fm] = *(bf16x8*)(Al + ((q >> 1) << 13) +
                      (((uint32_t)(r6 * 128 + kb)) ^ ((r6 & 7) << 4)));
        }
        int k0w = q * 8 + (lane >> 4) * 2;
#pragma unroll
        for (int fn = 0; fn < NAA; ++fn) {
            int b = pc[fn] >> 8;
            uint32_t c = (uint32_t)(pc[fn] & 0xff);
            uint2 ww = *(const uint2*)(xs + b * 130 + k0w);
            union { uint32_t u[4]; bf16x8 v; } pk;
#pragma unroll
            for (int pq = 0; pq < 4; ++pq) {
                uint32_t w = (pq < 2) ? ww.x : ww.y;
                uint32_t sh = (pq & 1) * 16;
                uint32_t b0 = (w >> sh) & 0xffu, b1 = (w >> (sh + 8)) & 0xffu;
                pk.u[pq] = ((b0 == c) ? 0x3F80u : 0u) | ((b1 == c) ? 0x3F800000u : 0u);
            }
            acc[0][fn] = __builtin_amdgcn_mfma_f32_16x16x32_bf16(af[0], pk.v, acc[0][fn], 0, 0, 0);
            acc[1][fn] = __builtin_amdgcn_mfma_f32_16x16x32_bf16(af[1], pk.v, acc[1][fn], 0, 0, 0);
        }
    }

    // ---- P3: 8 windows of 8 rows through Racc (stride 1349 f32)
    float vsum = 0.f;
    int bt = wv * 8 + (lane >> 3);     // this thread's batch
    int row = lane & 7;                // row within window
#pragma unroll
    for (int w = 0; w < 8; ++w) {
        __syncthreads();               // Racc free (prev window read done)
        if (wm == (w >> 2) && ((lane >> 4) >> 1) == (w & 1)) {
            int fm = (w >> 1) & 1;
            int lrb = ((lane >> 4) & 1) * 4;
#pragma unroll
            for (int fn = 0; fn < NAA; ++fn)
#pragma unroll
                for (int r = 0; r < 4; ++r)
                    Racc[(lrb + r) * 1349 + wn * 336 + fn * 16 + (lane & 15)] =
                        acc[fm][fn][r];
        }
        __syncthreads();               // window w written
        int ig = it * 64 + w * 8 + row;
        uint32_t xw = xs[bt * 130 + (ig >> 2)];
        int a = (int)((xw >> ((ig & 3) * 8)) & 0xffu);
        float rz = 1.0f / Zl[w * 8 + row];
        float dot = 0.f;
#pragma unroll
        for (int c = 0; c < NAA; ++c)
            dot += Vs[a * NAA + c] * Racc[row * 1349 + bt * 21 + c];
        vsum += dot * rz;
    }
    // reduce over the 8 rows of each batch group, one atomic per (wave, group)
    vsum += __shfl_xor(vsum, 1);
    vsum += __shfl_xor(vsum, 2);
    vsum += __shfl_xor(vsum, 4);
    if (row == 0) atomicAdd(&out[bt], -vsum);
}

// ---------------------------------------------------------------------------
extern "C" void kernel_launch(void* const* d_in, const int* in_sizes, int n_in,
                              void* d_out, int out_size, void* d_ws, size_t ws_size,
                              hipStream_t stream) {
    const int*   x = (const int*)d_in[0];
    const float* Q = (const float*)d_in[1];
    const float* K = (const float*)d_in[2];
    const float* V = (const float*)d_in[3];
    float* out = (float*)d_out;
    uint8_t* ws = (uint8_t*)d_ws;

    uint32_t* Qb = (uint32_t*)(ws + QB_OFF);
    uint32_t* Kb = (uint32_t*)(ws + KB_OFF);

    hipMemsetAsync(d_out, 0, NB * sizeof(float), stream);
    prep_qk<<<8192, 256, 0, stream>>>(Q, K, Qb, Kb);
    (void)hipFuncSetAttribute((const void*)fused_energy,
                              hipFuncAttributeMaxDynamicSharedMemorySize, FA_TOT);
    fused_energy<<<256, 512, FA_TOT, stream>>>((const uint8_t*)Qb, (const uint8_t*)Kb,
                                               x, V, out);
}